// Round 9
// baseline (89.877 us; speedup 1.0000x reference)
//
#include <hip/hip_runtime.h>

// DelayedXOR SH-SNN forward. Chains (b,h) fully independent; 1 thread/chain.
//
// Model (R5-R8, five consistent points): solo-wave VALU issue cadence is
// fixed at ~4.4 cyc/instr regardless of ILP -> wall = instr/step * 4.4.
// R8 measured ~16 instr/step. R9 cuts the spike path with cmp/cndmask:
//  - cmp W>1.0 directly (deletes the packed -1 sub; exact: Sterbenz on
//    [0.5,2] makes v-1 exact, sign preserved elsewhere -> (v-1)>0 <=> v>1)
//  - sf = cndmask(c,1,0) replaces ceil+med3
//  - q = cndmask(c0,oms,0) replaces the sf*oms multiply (bit-identical for
//    sf in {0,1}; 0 = +0 matches (1-as)*0)
// Two live bools -> two SGPR pairs, no VCC contention (R5 showed cmp/cndmask
// runs at the same 4.3 cadence). ~12 instr/step expected.
//
// Correctness: bit-exact fp32 vs numpy reference (absmax 0.0 in R1-R8).
// Skew (validated R7/R8): iteration j = v-step j + soma-step j-1; soma step
// -1 on zero state is an exact no-op; epilogue runs soma step 1023; acc
// window = Sf_768..Sf_1023 (tile 48 skips its first produced spike Sf_767).
// - fp contract OFF everywhere; exact reference expression order
// - sigmoid in double, rounded once to fp32

typedef float v2f __attribute__((ext_vector_type(2)));

// e[16] for tile k from plane-split LDS, packed 2 timesteps per op.
__device__ __forceinline__ void make_e(const float4* px0, const float4* px1,
                                       int k, float (&e)[16],
                                       v2f w02, v2f w12, v2f om2)
{
#pragma clang fp contract(off)
#pragma unroll
    for (int i4 = 0; i4 < 4; ++i4) {
        float4 a = px0[k * 4 + i4];   // x0 for steps 4*i4 .. 4*i4+3
        float4 c = px1[k * 4 + i4];   // x1 for same steps
        v2f pa0 = {a.x, a.y}, pa1 = {a.z, a.w};
        v2f pc0 = {c.x, c.y}, pc1 = {c.z, c.w};
        v2f E0 = om2 * ((pa0 * w02) + (pc0 * w12));
        v2f E1 = om2 * ((pa1 * w02) + (pc1 * w12));
        e[4*i4 + 0] = E0.x; e[4*i4 + 1] = E0.y;
        e[4*i4 + 2] = E1.x; e[4*i4 + 3] = E1.y;
    }
}

// ACCMODE: 0 = no acc, 1 = acc every soma step, 2 = acc all but first (j==0)
// Entry state: W = [v_{j-1}, V_{j-2}], SF = [sf_{j-1}, Sf_{j-2}],
// c0 = (sf_{j-1} == 1).
template <int ACCMODE>
__device__ __forceinline__ void tile16(const float (&e)[16],
                                       v2f AL, float oms,
                                       v2f& W, v2f& SF, bool& c0, float& acc)
{
#pragma clang fp contract(off)
#pragma unroll
    for (int j = 0; j < 16; ++j) {
        v2f A;
        A.x = e[j];                       // 1 mov
        A.y = c0 ? oms : 0.0f;            // q = (1-as)*sf_{j-1}, via cndmask
        v2f P = AL * W;                   // pk_mul: [ag*v, as*V]
        P = P + A;                        // pk_add
        W = P - SF;                       // pk_sub: [v_j, V_{j-1}]
        bool c0n = W.x > 1.0f;            // spike(v_j - 1)
        bool c1n = W.y > 1.0f;            // spike(V_{j-1} - 1)
        SF.x = c0n ? 1.0f : 0.0f;
        SF.y = c1n ? 1.0f : 0.0f;
        if (ACCMODE == 1 || (ACCMODE == 2 && j > 0))
            acc += SF.y;                  // Sf_{j-1}
        c0 = c0n;
    }
}

__global__ __launch_bounds__(64, 1) void snn_fwd(
    const float* __restrict__ x,       // [B, T, 2]
    const float* __restrict__ Wg,      // [2, 16, 2] == [h][2]
    const float* __restrict__ tau_m,   // [2, 16] == [h]
    const float* __restrict__ soma,    // [32]
    const float* __restrict__ W_out,   // [1, 32]
    const float* __restrict__ b_out,   // [1]
    float* __restrict__ out)           // [B, 1]
{
#pragma clang fp contract(off)
    // Plane-split LDS: x0/x1 separated so adjacent timesteps are adjacent.
    __shared__ float sx0[2][1024];
    __shared__ float sx1[2][1024];

    const int tid  = threadIdx.x;
    const int h    = tid & 31;
    const int half = tid >> 5;
    const int b    = (blockIdx.x << 1) | half;

    // Cooperative staging with x0/x1 de-interleave.
    const float4* gx = (const float4*)(x + (size_t)blockIdx.x * 4096);
#pragma unroll
    for (int k = 0; k < 16; ++k) {
        int i = k * 64 + tid;
        int row = i >> 9, p = i & 511;
        float4 q = gx[i];
        *(float2*)&sx0[row][2*p] = make_float2(q.x, q.z);
        *(float2*)&sx1[row][2*p] = make_float2(q.y, q.w);
    }

    const float w0 = Wg[2*h + 0];
    const float w1 = Wg[2*h + 1];
    const float ag  = (float)(1.0 / (1.0 + exp(-(double)tau_m[h])));
    const float omg = 1.0f - ag;
    const float as  = (float)(1.0 / (1.0 + exp(-(double)soma[h])));
    const float oms = 1.0f - as;

    const v2f w02 = {w0, w0}, w12 = {w1, w1}, om2 = {omg, omg};
    const v2f AL  = {ag, as};

    __syncthreads();

    const float4* px0 = (const float4*)sx0[half];
    const float4* px1 = (const float4*)sx1[half];

    v2f W  = {0.f, 0.f};   // [v, V] (skewed)
    v2f SF = {0.f, 0.f};   // [sf, Sf] (skewed)
    bool c0 = false;
    float acc = 0.f;

    float eA[16], eB[16];
    make_e(px0, px1, 0, eA, w02, w12, om2);

    // tiles 0..47: soma steps <= 766 -> no acc
    for (int k = 0; k < 48; k += 2) {
        make_e(px0, px1, k + 1, eB, w02, w12, om2);
        tile16<0>(eA, AL, oms, W, SF, c0, acc);
        make_e(px0, px1, k + 2, eA, w02, w12, om2);
        tile16<0>(eB, AL, oms, W, SF, c0, acc);
    }
    // tile 48: produces Sf_767..782 -> acc all but first
    make_e(px0, px1, 49, eB, w02, w12, om2);
    tile16<2>(eA, AL, oms, W, SF, c0, acc);
    // tiles 49..63: acc all
    make_e(px0, px1, 50, eA, w02, w12, om2);
    tile16<1>(eB, AL, oms, W, SF, c0, acc);
    for (int k = 50; k < 62; k += 2) {
        make_e(px0, px1, k + 1, eB, w02, w12, om2);
        tile16<1>(eA, AL, oms, W, SF, c0, acc);
        make_e(px0, px1, k + 2, eA, w02, w12, om2);
        tile16<1>(eB, AL, oms, W, SF, c0, acc);
    }
    make_e(px0, px1, 63, eB, w02, w12, om2);
    tile16<1>(eA, AL, oms, W, SF, c0, acc);
    tile16<1>(eB, AL, oms, W, SF, c0, acc);

    // epilogue: soma step 1023 (consumes sf_1023 = c0)
    {
        float a1 = as * W.y;
        float a2 = c0 ? oms : 0.0f;
        float a3 = a1 + a2;
        float Vn = a3 - SF.y;
        acc += (Vn > 1.0f) ? 1.0f : 0.0f;
    }

    // out[b] = sum_h acc[h] * W_out[h] + b_out; xor-reduce within 32-lane half.
    float val = acc * W_out[h];
#pragma unroll
    for (int m = 16; m >= 1; m >>= 1)
        val += __shfl_xor(val, m, 64);
    if ((tid & 31) == 0)
        out[b] = val + b_out[0];
}

extern "C" void kernel_launch(void* const* d_in, const int* in_sizes, int n_in,
                              void* d_out, int out_size, void* d_ws, size_t ws_size,
                              hipStream_t stream)
{
    const float* x     = (const float*)d_in[0];
    const float* Wg    = (const float*)d_in[1];
    const float* tau_m = (const float*)d_in[2];
    const float* soma  = (const float*)d_in[3];
    const float* W_out = (const float*)d_in[4];
    const float* b_out = (const float*)d_in[5];
    float* out = (float*)d_out;

    // 512 blocks x 64 threads = one (b,h) chain per thread.
    dim3 grid(512), block(64);
    hipLaunchKernelGGL(snn_fwd, grid, block, 0, stream,
                       x, Wg, tau_m, soma, W_out, b_out, out);
}